// Round 13
// baseline (158.457 us; speedup 1.0000x reference)
//
#include <hip/hip_runtime.h>

typedef unsigned short u16;
typedef unsigned int u32;
typedef __attribute__((ext_vector_type(8))) short short8;
typedef __attribute__((ext_vector_type(4))) float f32x4;

#define GLOBAL_AS(p) (const __attribute__((address_space(1))) void*)(p)
#define LDS_AS(p) (__attribute__((address_space(3))) void*)(p)

__device__ __forceinline__ u16 f2b(float f) {
  u32 u = __float_as_uint(f);
  u32 r = (u + 0x7fffu + ((u >> 16) & 1u)) >> 16;
  return (u16)r;
}
__device__ __forceinline__ float blo(u32 u) { return __uint_as_float(u << 16); }
__device__ __forceinline__ float bhi(u32 u) { return __uint_as_float(u & 0xffff0000u); }

// ---------------- fp32 -> bf16 convert (x) ----------------
__global__ void conv_bf16(const float* __restrict__ in, u16* __restrict__ out, int n4) {
  int i = blockIdx.x * blockDim.x + threadIdx.x;
  int stride = gridDim.x * blockDim.x;
  for (; i < n4; i += stride) {
    float4 f = ((const float4*)in)[i];
    ushort4 u;
    u.x = f2b(f.x); u.y = f2b(f.y); u.z = f2b(f.z); u.w = f2b(f.w);
    ((ushort4*)out)[i] = u;
  }
}

// ---- fused weight transpose+convert: z=0 w_qkv(768x2304), z=1 w_proj(768x768) ----
__global__ void transpose_conv2(const float* __restrict__ w_qkv, u16* __restrict__ wqT,
                                const float* __restrict__ w_proj, u16* __restrict__ wpT) {
  __shared__ float tile[32][33];
  const int z = blockIdx.z;
  if (z && blockIdx.x >= 24) return;
  const float* in = z ? w_proj : w_qkv;
  u16* out = z ? wpT : wqT;
  const int Cc = z ? 768 : 2304;
  int c0 = blockIdx.x * 32, r0 = blockIdx.y * 32;
  int tx = threadIdx.x, ty = threadIdx.y;  // 32 x 8
#pragma unroll
  for (int i = 0; i < 32; i += 8)
    tile[ty + i][tx] = in[(size_t)(r0 + ty + i) * Cc + c0 + tx];
  __syncthreads();
#pragma unroll
  for (int i = 0; i < 32; i += 8)
    out[(size_t)(c0 + ty + i) * 768 + r0 + tx] = f2b(tile[tx][ty + i]);
}

// ---------------- GEMM: C = A(MxK) * Bt(NxK)^T, bf16 in, fp32 acc ----------------
// BM=256, BN=NFRAG*16 (144 or 96), BK=64, K=768 (12 tiles). 512 threads = 8
// waves, wave wv owns rows [wv*32, wv*32+32) x all BN cols. 3-buffer LDS ring,
// depth-2 prefetch, counted per-wave vmcnt, setprio. Software-pipelined frag
// reads (read-ahead across barrier pair): per iter
//   bar1; STAGE(kt+2); read h1(kt); MFMA h0(kt); vmcnt(S); bar2;
//   read h0(kt+1); MFMA h1(kt)
// so each MFMA cluster overlaps the other half's ds_reads. vmcnt+bar2 makes
// the tile-(kt+1) confirmation COLLECTIVE before the read-ahead touches it.
// Swizzle chunk^=(row&7) on BOTH staging source and ds_read. Exact CU fills.

#define GLD(SRC, DST) __builtin_amdgcn_global_load_lds(GLOBAL_AS(SRC), LDS_AS(DST), 16, 0, 0)
#define WAITN(n) asm volatile("s_waitcnt vmcnt(" #n ")" ::: "memory")

#define WAITSEL                                                                          \
  do {                                                                                   \
    if (NBCH >= 1024) { if (wex) WAITN(7); else WAITN(6); }                              \
    else              { if (wex) WAITN(6); else WAITN(5); }                              \
  } while (0)

#define STAGEW(KT, SB)                                                                   \
  do {                                                                                   \
    const u16* a_ = gA0 + (KT) * 64;                                                     \
    GLD(a_,            lA + (SB) * 16384 + t * 8);                                       \
    GLD(a_ + 64 * kk,  lA + (SB) * 16384 + (t + 512) * 8);                               \
    GLD(a_ + 128 * kk, lA + (SB) * 16384 + (t + 1024) * 8);                              \
    GLD(a_ + 192 * kk, lA + (SB) * 16384 + (t + 1536) * 8);                              \
    const u16* b_ = gB0 + (KT) * 64;                                                     \
    GLD(b_, lB + (SB) * TBSZ + t * 8);                                                   \
    if (NBCH >= 1024) {                                                                  \
      GLD(b_ + 64 * kk, lB + (SB) * TBSZ + (t + 512) * 8);                               \
      if (t < NBCH - 1024) GLD(b_ + 128 * kk, lB + (SB) * TBSZ + (t + 1024) * 8);        \
    } else {                                                                             \
      if (t < NBCH - 512) GLD(b_ + 64 * kk, lB + (SB) * TBSZ + (t + 512) * 8);           \
    }                                                                                    \
  } while (0)

#define READH(A0, A1, BARR, BUF, CS)                                                     \
  do {                                                                                   \
    const u16* pa_ = lA + (BUF) * 16384;                                                 \
    const u16* pb_ = lB + (BUF) * TBSZ;                                                  \
    A0 = *(const short8*)(pa_ + arow0 + (CS));                                           \
    A1 = *(const short8*)(pa_ + arow1 + (CS));                                           \
    _Pragma("unroll")                                                                    \
    for (int ni = 0; ni < NFRAG; ++ni)                                                   \
      BARR[ni] = *(const short8*)(pb_ + ni * 1024 + browb + (CS));                       \
  } while (0)

#define MFMA2N(A0, A1, BARR)                                                             \
  do {                                                                                   \
    __builtin_amdgcn_s_setprio(1);                                                       \
    _Pragma("unroll")                                                                    \
    for (int ni = 0; ni < NFRAG; ++ni) {                                                 \
      acc[0][ni] = __builtin_amdgcn_mfma_f32_16x16x32_bf16(A0, BARR[ni], acc[0][ni], 0, 0, 0); \
      acc[1][ni] = __builtin_amdgcn_mfma_f32_16x16x32_bf16(A1, BARR[ni], acc[1][ni], 0, 0, 0); \
    }                                                                                    \
    __builtin_amdgcn_s_setprio(0);                                                       \
  } while (0)

// One K-iter: tile KT from buffer CB, read-ahead tile KT+1 from NB, stage into SB.
#define ITERP(KT, CB, NB, SB)                                                            \
  do {                                                                                   \
    __builtin_amdgcn_s_barrier();                                                        \
    asm volatile("" ::: "memory");                                                       \
    STAGEW((KT) + 2, SB);                                                                \
    READH(xA0, xA1, xB, CB, cs1);  /* tile KT half1 */                                   \
    MFMA2N(cA0, cA1, cB);          /* tile KT half0 */                                   \
    WAITSEL;                       /* own loads of tile KT+1 landed */                   \
    __builtin_amdgcn_s_barrier();  /* collective confirmation */                         \
    asm volatile("" ::: "memory");                                                       \
    READH(cA0, cA1, cB, NB, cs0);  /* tile KT+1 half0 (read-ahead) */                    \
    MFMA2N(xA0, xA1, xB);          /* tile KT half1 */                                   \
  } while (0)

template <int EPI, int NFRAG>
__global__ __launch_bounds__(512, 2) void gemmP(
    const u16* __restrict__ A, const u16* __restrict__ Bt, void* __restrict__ Cout,
    const float* __restrict__ bias, int M, int N, int K, int NXP) {
  constexpr int NBCH = NFRAG * 128;
  constexpr int TBSZ = NFRAG * 1024;
  constexpr int EXW = (NBCH >= 1024 ? NBCH - 1024 : NBCH - 512) / 64;
  extern __shared__ u16 sm[];
  u16* lA = sm;
  u16* lB = sm + 3 * 16384;
  const int t = threadIdx.x;
  const size_t kk = (size_t)K;
  const int nwg = gridDim.x;
  const int logical = (blockIdx.x & 7) * (nwg >> 3) + (blockIdx.x >> 3);
  const int m0 = (logical / NXP) * 256;
  const int n0 = (logical % NXP) * (NFRAG * 16);
  const int wv = t >> 6, l = t & 63;
  const int lr = l & 15, g = l >> 4;
  const bool wex = wv < EXW;

  const int ra = t >> 3;
  const int ca = (t & 7) ^ (ra & 7);
  const u16* gA0 = A + (size_t)(m0 + ra) * kk + ca * 8;
  const u16* gB0 = Bt + (size_t)(n0 + ra) * kk + ca * 8;

  const int cs0 = ((g + 0) ^ (lr & 7)) * 8;
  const int cs1 = ((g + 4) ^ (lr & 7)) * 8;
  const int arow0 = (wv * 32 + lr) * 64, arow1 = (wv * 32 + 16 + lr) * 64;
  const int browb = lr * 64;

  f32x4 acc[2][NFRAG] = {};
  short8 cA0, cA1, cB[NFRAG], xA0, xA1, xB[NFRAG];

  STAGEW(0, 0);
  STAGEW(1, 1);
  WAITSEL;                        // own tile-0 loads landed
  __builtin_amdgcn_s_barrier();   // collective
  asm volatile("" ::: "memory");
  READH(cA0, cA1, cB, 0, cs0);    // tile 0 half0

  // K=768 -> 12 tiles. Iters 0..9 stage kt+2; buffer pattern period 3.
  int kt = 0;
  for (int j = 0; j < 3; ++j) {
    ITERP(kt, 0, 1, 2); ++kt;
    ITERP(kt, 1, 2, 0); ++kt;
    ITERP(kt, 2, 0, 1); ++kt;
  }
  ITERP(9, 0, 1, 2);              // kt=9: stages tile 11 into buf 2

  // kt=10 (buf 1), read-ahead tile 11 (buf 2): no more staging
  READH(xA0, xA1, xB, 1, cs1);    // tile 10 half1
  MFMA2N(cA0, cA1, cB);           // tile 10 half0
  WAITN(0);                       // own tile-11 loads landed
  __builtin_amdgcn_s_barrier();   // collective
  asm volatile("" ::: "memory");
  READH(cA0, cA1, cB, 2, cs0);    // tile 11 half0
  MFMA2N(xA0, xA1, xB);           // tile 10 half1
  // kt=11 (buf 2)
  READH(xA0, xA1, xB, 2, cs1);    // tile 11 half1
  MFMA2N(cA0, cA1, cB);           // tile 11 half0
  MFMA2N(xA0, xA1, xB);           // tile 11 half1

#pragma unroll
  for (int mi = 0; mi < 2; ++mi) {
    int row = m0 + wv * 32 + mi * 16 + g * 4;
#pragma unroll
    for (int ni = 0; ni < NFRAG; ++ni) {
      int col = n0 + ni * 16 + lr;
#pragma unroll
      for (int r = 0; r < 4; ++r) {
        float v = acc[mi][ni][r];
        if (EPI == 0) {
          ((u16*)Cout)[(size_t)(row + r) * N + col] = f2b(v);
        } else {
          ((float*)Cout)[(size_t)(row + r) * N + col] = v + bias[col];
        }
      }
    }
  }
}

// ---------------- local attention (4 threads per row) ----------------
// qkv: (B*N, 2304) bf16 rows: [q | k | v], within each: h*64+d.
// Block: 512 threads = (row r = t>>2, quarter p = t&3), NTILE=128 rows, 1 head.
#define NTILE 128
#define ROWS 140  // NTILE + 2*6
#define LPAD 66

__global__ __launch_bounds__(512, 6) void attn_kernel(const u16* __restrict__ qkv,
                                                      u16* __restrict__ attn) {
  const int nt = blockIdx.x, h = blockIdx.y, b = blockIdx.z;
  const int n0 = nt * NTILE;
  const int t = threadIdx.x;
  __shared__ u16 kl[ROWS * LPAD];
  __shared__ u16 vl[ROWS * LPAD];

  for (int i = t; i < 2 * ROWS * 8; i += 512) {
    int mat = i >= ROWS * 8;
    int j = mat ? i - ROWS * 8 : i;
    int r = j >> 3, c = j & 7;
    int grow = n0 - 6 + r;
    grow = grow < 0 ? 0 : (grow > 4095 ? 4095 : grow);
    const uint4 u =
        *(const uint4*)(qkv + (size_t)(b * 4096 + grow) * 2304 + (mat ? 1536 : 768) + h * 64 + c * 8);
    u16* dst = (mat ? vl : kl) + r * LPAD + c * 8;
    ((u32*)dst)[0] = u.x;
    ((u32*)dst)[1] = u.y;
    ((u32*)dst)[2] = u.z;
    ((u32*)dst)[3] = u.w;
  }
  __syncthreads();

  const int r = t >> 2;
  const int p = t & 3;
  const int n = n0 + r;
  const int dbase = p * 16;

  float qf[16];
  const u16* qp = qkv + (size_t)(b * 4096 + n) * 2304 + h * 64 + dbase;
#pragma unroll
  for (int c = 0; c < 2; ++c) {
    uint4 u = *(const uint4*)(qp + c * 8);
    qf[c * 8 + 0] = blo(u.x); qf[c * 8 + 1] = bhi(u.x);
    qf[c * 8 + 2] = blo(u.y); qf[c * 8 + 3] = bhi(u.y);
    qf[c * 8 + 4] = blo(u.z); qf[c * 8 + 5] = bhi(u.z);
    qf[c * 8 + 6] = blo(u.w); qf[c * 8 + 7] = bhi(u.w);
  }

  float s[13];
#pragma unroll
  for (int w = 0; w < 13; ++w) s[w] = 0.f;
#pragma unroll
  for (int d2 = 0; d2 < 8; ++d2) {
    float q0 = qf[2 * d2], q1 = qf[2 * d2 + 1];
#pragma unroll
    for (int w = 0; w < 13; ++w) {
      u32 u = *(const u32*)(kl + (r + w) * LPAD + dbase + 2 * d2);
      s[w] += q0 * blo(u) + q1 * bhi(u);
    }
  }
#pragma unroll
  for (int w = 0; w < 13; ++w) {
    s[w] += __shfl_xor(s[w], 1);
    s[w] += __shfl_xor(s[w], 2);
  }

#pragma unroll
  for (int w = 0; w < 13; ++w) {
    int nn = n - 6 + w;
    s[w] = (nn >= 0 && nn < 4096) ? s[w] * 0.125f : -1e30f;
  }
  float m = s[0];
#pragma unroll
  for (int w = 1; w < 13; ++w) m = fmaxf(m, s[w]);
  float sum = 0.f;
#pragma unroll
  for (int w = 0; w < 13; ++w) {
    float pr = __expf(s[w] - m);
    s[w] = pr;
    sum += pr;
  }
  float inv = 1.0f / sum;

  float o[16];
#pragma unroll
  for (int d = 0; d < 16; ++d) o[d] = 0.f;
#pragma unroll
  for (int w = 0; w < 13; ++w) {
    float pw = s[w] * inv;
#pragma unroll
    for (int d2 = 0; d2 < 8; ++d2) {
      u32 u = *(const u32*)(vl + (r + w) * LPAD + dbase + 2 * d2);
      o[2 * d2] += pw * blo(u);
      o[2 * d2 + 1] += pw * bhi(u);
    }
  }

  u16* op = attn + (size_t)(b * 4096 + n) * 768 + h * 64 + dbase;
#pragma unroll
  for (int c = 0; c < 2; ++c) {
    uint4 u;
    u.x = (u32)f2b(o[c * 8 + 0]) | ((u32)f2b(o[c * 8 + 1]) << 16);
    u.y = (u32)f2b(o[c * 8 + 2]) | ((u32)f2b(o[c * 8 + 3]) << 16);
    u.z = (u32)f2b(o[c * 8 + 4]) | ((u32)f2b(o[c * 8 + 5]) << 16);
    u.w = (u32)f2b(o[c * 8 + 6]) | ((u32)f2b(o[c * 8 + 7]) << 16);
    ((uint4*)op)[c] = u;
  }
}

extern "C" void kernel_launch(void* const* d_in, const int* in_sizes, int n_in,
                              void* d_out, int out_size, void* d_ws, size_t ws_size,
                              hipStream_t stream) {
  const float* x = (const float*)d_in[0];
  const float* w_qkv = (const float*)d_in[1];
  const float* w_proj = (const float*)d_in[2];
  const float* b_proj = (const float*)d_in[3];
  float* out = (float*)d_out;

  char* p = (char*)d_ws;
  u16* xb = (u16*)p;     p += (size_t)8192 * 768 * 2;
  u16* wqT = (u16*)p;    p += (size_t)2304 * 768 * 2;
  u16* wpT = (u16*)p;    p += (size_t)768 * 768 * 2;
  u16* qkvb = (u16*)p;   p += (size_t)8192 * 2304 * 2;
  u16* attnb = (u16*)p;  p += (size_t)8192 * 768 * 2;

  const int lds1 = 3 * (32768 + 18432);
  const int lds2 = 3 * (32768 + 12288);
  hipFuncSetAttribute((const void*)gemmP<0, 9>, hipFuncAttributeMaxDynamicSharedMemorySize, lds1);
  hipFuncSetAttribute((const void*)gemmP<1, 6>, hipFuncAttributeMaxDynamicSharedMemorySize, lds2);

  conv_bf16<<<dim3(2048), dim3(256), 0, stream>>>(x, xb, 8192 * 768 / 4);
  transpose_conv2<<<dim3(72, 24, 2), dim3(32, 8), 0, stream>>>(w_qkv, wqT, w_proj, wpT);

  // gemm1: M=8192 (32 x 256), N=2304 (16 x 144) -> 512 blocks = 2 exact fills
  gemmP<0, 9><<<dim3(512), dim3(512), lds1, stream>>>(
      xb, wqT, (void*)qkvb, nullptr, 8192, 2304, 768, 16);

  attn_kernel<<<dim3(4096 / NTILE, 12, 2), dim3(512), 0, stream>>>(qkvb, attnb);

  // gemm2: M=8192 (32 x 256), N=768 (8 x 96) -> 256 blocks = 1 exact fill
  gemmP<1, 6><<<dim3(256), dim3(512), lds2, stream>>>(
      attnb, wpT, (void*)out, b_proj, 8192, 768, 768, 8);
}